// Round 8
// baseline (146.311 us; speedup 1.0000x reference)
//
#include <hip/hip_runtime.h>

typedef float f32x2 __attribute__((ext_vector_type(2)));
typedef _Float16 h2 __attribute__((ext_vector_type(2)));

constexpr float LOG2E = 1.4426950408889634f;
#define TBIG 3.0e38f
#define PD 38          // padded grid dim (32 + 2*3 halo)
#define PD2 1444       // 38*38
#define NPC 54872      // 38^3 padded cells

// ---- per-parity offset tables (123 offsets r2<=9 sorted by r2, split even/odd) ----
// ti: {tci*32, r2, packed(dx+3|dy+3<<8|dz+3<<16), 0}   tf: {2dx, 2dy, 2dz, 0}
struct Tabs { int ti[2][62][4]; float tf[2][62][4]; };
constexpr Tabs make_tabs() {
    int dxs[123], dys[123], dzs[123]; int n = 0;
    for (int rr = 0; rr <= 9; ++rr)
        for (int a = -3; a <= 3; ++a)
            for (int b = -3; b <= 3; ++b)
                for (int c = -3; c <= 3; ++c)
                    if (a*a + b*b + c*c == rr) { dxs[n]=a; dys[n]=b; dzs[n]=c; ++n; }
    Tabs T{};
    for (int p = 0; p < 2; ++p)
        for (int j = 0; j < 62; ++j) {
            int k = 2*j + p;
            if (k < 123) {
                int a = dxs[k], b = dys[k], c = dzs[k];
                int tci = (a*PD + b)*PD + c;
                T.ti[p][j][0] = tci*32;
                T.ti[p][j][1] = a*a + b*b + c*c;
                T.ti[p][j][2] = (a+3) | ((b+3)<<8) | ((c+3)<<16);
                T.tf[p][j][0] = 2.f*a; T.tf[p][j][1] = 2.f*b; T.tf[p][j][2] = 2.f*c;
            } else {
                T.ti[p][j][0] = 0; T.ti[p][j][1] = 999; T.ti[p][j][2] = 3 | (3<<8) | (3<<16);
            }
        }
    return T;
}
__constant__ Tabs TB = make_tabs();

__device__ __forceinline__ float fast_exp2(float x) { return __builtin_amdgcn_exp2f(x); }

// ---------------- prep AB (padded): sigma reciprocals + guide downsample + sigEff ----------------
__device__ __forceinline__ void mk_taps(int j, int idx[4], float wt[4]) {
    float s = 0.f;
#pragma unroll
    for (int k = 0; k < 4; ++k) {
        int i = 2*j - 1 + k;
        float w = (k == 0 || k == 3) ? 0.25f : 0.75f;
        bool ok = (i >= 0) && (i < 64);
        wt[k] = ok ? w : 0.f;
        idx[k] = ok ? i : 0;
        s += wt[k];
    }
    float inv = 1.f / s;
#pragma unroll
    for (int k = 0; k < 4; ++k) wt[k] *= inv;
}

__global__ void prepABpad(const float* __restrict__ sxr, const float* __restrict__ syr,
                          const float* __restrict__ szr, const float* __restrict__ srr,
                          const float* __restrict__ guide,
                          float4* __restrict__ param4, float* __restrict__ sigEff) {
    int t = blockIdx.x * 256 + threadIdx.x;
    if (t >= NPC) return;
    int pu = t / PD2; int rem = t - pu*PD2; int pv = rem / PD; int pw = rem - pv*PD;
    int u = min(max(pu-3, 0), 31), v = min(max(pv-3, 0), 31), w = min(max(pw-3, 0), 31);
    int ci = (u*32 + v)*32 + w;
    float sx = fmaxf(expf(sxr[ci]), 1e-6f);
    float sy = fmaxf(expf(syr[ci]), 1e-6f);
    float sz = fmaxf(expf(szr[ci]), 1e-6f);
    float sr = fmaxf(expf(srr[ci]), 1e-6f);
    param4[2*t] = make_float4(0.5f/(sx*sx), 0.5f/(sy*sy), 0.5f/(sz*sz), 1.0f/(2.0f*sr*sr + 1e-8f));
    if (pu-3 == u && pv-3 == v && pw-3 == w) sigEff[ci] = fmaxf(sx, fmaxf(sy, sz));

    int iu[4], iv[4], iw[4];
    float wu[4], wv[4], ww[4];
    mk_taps(u, iu, wu); mk_taps(v, iv, wv); mk_taps(w, iw, ww);
    float g0 = 0.f, g1 = 0.f, g2 = 0.f;
#pragma unroll
    for (int a = 0; a < 4; ++a)
#pragma unroll
        for (int b = 0; b < 4; ++b) {
            float wab = wu[a]*wv[b];
            int base = iu[a]*4096 + iv[b]*64;
#pragma unroll
            for (int c = 0; c < 4; ++c) {
                float wt = wab*ww[c];
                int gi = base + iw[c];
                g0 += wt*guide[gi];
                g1 += wt*guide[262144 + gi];
                g2 += wt*guide[524288 + gi];
            }
        }
    param4[2*t + 1] = make_float4(g0, g1, g2, 0.f);
}

// ---------------- prep T: feat [c][u][v][w] -> padded featH [pu][pv][pw][c] f16 (interior) ----------------
__global__ void prepTpad(const float* __restrict__ feat, _Float16* __restrict__ featH) {
    __shared__ float tile[32][33];
    int uv = blockIdx.x;
    int u = uv >> 5, v = uv & 31;
    int col = threadIdx.x & 31;
    int row = threadIdx.x >> 5;
#pragma unroll
    for (int it = 0; it < 4; ++it) {
        int c = row + it*8;
        tile[c][col] = feat[((c*32 + u)*32 + v)*32 + col];
    }
    __syncthreads();
#pragma unroll
    for (int it = 0; it < 4; ++it) {
        int w = row + it*8;
        int pci = (u+3)*PD2 + (v+3)*PD + (w+3);
        featH[pci*32 + col] = (_Float16)tile[col][w];
    }
}

// ---------------- prep border: replicate edge feature records into the halo ----------------
__global__ void prepBorder(_Float16* __restrict__ featH) {
    int t = blockIdx.x * 256 + threadIdx.x;
    if (t >= NPC) return;
    int pu = t / PD2; int rem = t - pu*PD2; int pv = rem / PD; int pw = rem - pv*PD;
    int u = min(max(pu-3, 0), 31), v = min(max(pv-3, 0), 31), w = min(max(pw-3, 0), 31);
    if (pu-3 == u && pv-3 == v && pw-3 == w) return;
    int src = ((u+3)*PD2 + (v+3)*PD + (w+3))*32;
    uint4* d = (uint4*)(featH + t*32);
    const uint4* s = (const uint4*)(featH + src);
    d[0] = s[0]; d[1] = s[1]; d[2] = s[2]; d[3] = s[3];
}

// ---- two-chunk stash-and-accumulate body (31 offsets per chunk, fully unrolled) ----
// Scale invariant: num2[r] is ALWAYS at quad-member r's per-voxel scale M_r; every rescale
// of num2[r] uses r's factor (shuffled), den uses own factor. (R7 bug: used own factor for all r.)
template<bool INTER>
__device__ __forceinline__ void body(const float4* __restrict__ param4,
                                     const _Float16* __restrict__ featH,
                                     int par, int pbase, int fbase, int jcount, int R2i,
                                     int uc, int vc, int wc,
                                     float exf, float eyf, float ezf,
                                     float Xh, float Yh, float Zh,
                                     float G0, float G1, float G2,
                                     f32x2 (&num2)[4][4], float& den, float& M) {
    for (int c = 0; c < 2; ++c) {
        float tts[31];
        float cmin = TBIG;
#pragma unroll
        for (int j = 0; j < 31; ++j) {
            int jg = c*31 + j;
            int e0  = TB.ti[par][jg][0];
            int er2 = TB.ti[par][jg][1];
            const char* pA = (const char*)param4 + (pbase + e0);
            float4 A  = *(const float4*)pA;
            float4 Bv = *(const float4*)(pA + 16);
            float ddx, ddy, ddz;
            if (INTER) {
                ddx = exf - TB.tf[par][jg][0];
                ddy = eyf - TB.tf[par][jg][1];
                ddz = ezf - TB.tf[par][jg][2];
            } else {
                int epk = TB.ti[par][jg][2];
                int Ui = min(max(uc + ((epk & 255) - 3), 0), 31);
                int Vi = min(max(vc + (((epk >> 8) & 255) - 3), 0), 31);
                int Wi = min(max(wc + ((epk >> 16) - 3), 0), 31);
                ddx = fmaf(-2.f, (float)Ui, Xh);
                ddy = fmaf(-2.f, (float)Vi, Yh);
                ddz = fmaf(-2.f, (float)Wi, Zh);
            }
            float tt = fmaf(ddx*ddx, A.x, fmaf(ddy*ddy, A.y, ddz*ddz*A.z));
            float d0 = G0 - Bv.x, d1 = G1 - Bv.y, d2 = G2 - Bv.z;
            tt = fmaf(fmaf(d0, d0, fmaf(d1, d1, d2*d2)), A.w, tt);
            int r2e = (jg < jcount) ? er2 : 999;
            tt = (r2e <= R2i) ? tt : TBIG;
            tts[j] = tt;
            cmin = fminf(cmin, tt);
        }
        // cross-chunk online rescale (2 per wave, exact); factors shuffled per quad member
        float Mn = fminf(M, cmin);
        float f = fast_exp2((Mn - M) * LOG2E);
        M = Mn;
        float f1 = __shfl_xor(f, 1), f8 = __shfl_xor(f, 8), f9 = __shfl_xor(f, 9);
        den *= f;
        f32x2 fv0 = {f, f}, fv1 = {f1, f1}, fv2 = {f8, f8}, fv3 = {f9, f9};
#pragma unroll
        for (int p = 0; p < 4; ++p) {
            num2[0][p] *= fv0;
            num2[1][p] *= fv1;
            num2[2][p] *= fv2;
            num2[3][p] *= fv3;
        }
        float MLc = M * LOG2E;
#pragma unroll
        for (int j = 0; j < 31; ++j) {
            int jg = c*31 + j;
            int e0 = TB.ti[par][jg][0];
            float wgt = fast_exp2(fmaf(tts[j], -LOG2E, MLc));  // masked -> -inf -> 0
            den += wgt;
            float w1 = __shfl_xor(wgt, 1), w8 = __shfl_xor(wgt, 8), w9 = __shfl_xor(wgt, 9);
            float4 F = *(const float4*)(featH + (fbase + e0));
            h2 q0 = __builtin_bit_cast(h2, F.x);
            h2 q1 = __builtin_bit_cast(h2, F.y);
            h2 q2 = __builtin_bit_cast(h2, F.z);
            h2 q3 = __builtin_bit_cast(h2, F.w);
            f32x2 f0 = {(float)q0.x, (float)q0.y};
            f32x2 f1v = {(float)q1.x, (float)q1.y};
            f32x2 f2v = {(float)q2.x, (float)q2.y};
            f32x2 f3v = {(float)q3.x, (float)q3.y};
            f32x2 w0v = {wgt, wgt}, w1v = {w1, w1}, w2v = {w8, w8}, w3v = {w9, w9};
            num2[0][0] += f0*w0v;  num2[0][1] += f1v*w0v; num2[0][2] += f2v*w0v; num2[0][3] += f3v*w0v;
            num2[1][0] += f0*w1v;  num2[1][1] += f1v*w1v; num2[1][2] += f2v*w1v; num2[1][3] += f3v*w1v;
            num2[2][0] += f0*w2v;  num2[2][1] += f1v*w2v; num2[2][2] += f2v*w2v; num2[2][3] += f3v*w2v;
            num2[3][0] += f0*w3v;  num2[3][1] += f1v*w3v; num2[3][2] += f2v*w3v; num2[3][3] += f3v*w3v;
        }
    }
}

// ---- main: 2 waves per 8x8 (Y,Z) tile (even/odd offsets), quads share LR cell ----
__global__ __launch_bounds__(256, 4)
void jbu_main(const float* __restrict__ guide, const float4* __restrict__ param4,
              const float* __restrict__ sigEff, const _Float16* __restrict__ featH,
              float* __restrict__ out) {
    __shared__ float mbuf[2][64][34];   // {num[32], den, M} per voxel-lane
    int tid = threadIdx.x;
    int widx = tid >> 6;
    int l = tid & 63;
    int par = widx & 1;
    int q = widx >> 1;
    // XCD-bijective swizzle: 2048 blocks, XCD k owns X in [8k, 8k+8)
    int bsw = (blockIdx.x & 7) * 256 + (blockIdx.x >> 3);
    int tIdx = bsw * 2 + q;             // 4096 tiles
    int X = tIdx >> 6;
    int Y0 = ((tIdx >> 3) & 7) << 3;
    int Z0 = (tIdx & 7) << 3;
    int y = l >> 3, z = l & 7;
    int Y = Y0 + y, Z = Z0 + z;
    int h = ((y & 1) << 1) | (z & 1);
    int vox = (X << 12) + (Y << 6) + Z;

    float G0 = guide[vox];
    float G1 = guide[262144 + vox];
    float G2 = guide[524288 + vox];

    // sigma_eff_hr: 2x trilinear upsample with clamped taps -> R2i
    int x0 = max((X-1) >> 1, 0), x1 = min(((X-1) >> 1) + 1, 31);
    int y0 = max((Y-1) >> 1, 0), y1 = min(((Y-1) >> 1) + 1, 31);
    int z0 = max((Z-1) >> 1, 0), z1 = min(((Z-1) >> 1) + 1, 31);
    float wx1 = (X & 1) ? 0.25f : 0.75f, wx0 = 1.f - wx1;
    float wy1 = (Y & 1) ? 0.25f : 0.75f, wy0 = 1.f - wy1;
    float wz1 = (Z & 1) ? 0.25f : 0.75f, wz0 = 1.f - wz1;
#define SG(i, j, k) sigEff[((i)*32 + (j))*32 + (k)]
    float se =
        wx0*(wy0*(wz0*SG(x0,y0,z0) + wz1*SG(x0,y0,z1)) +
             wy1*(wz0*SG(x0,y1,z0) + wz1*SG(x0,y1,z1))) +
        wx1*(wy0*(wz0*SG(x1,y0,z0) + wz1*SG(x1,y0,z1)) +
             wy1*(wz0*SG(x1,y1,z0) + wz1*SG(x1,y1,z1)));
#undef SG
    float Rf = fminf(fmaxf(ceilf(2.f*se), 1.f), 3.f);
    int R2i = (int)(Rf*Rf + 0.5f);
    bool a9 = __any((int)(R2i >= 9));
    bool a4 = __any((int)(R2i >= 4));
    int nmax = a9 ? 123 : (a4 ? 33 : 7);
    int jcount = (nmax - par + 1) >> 1;

    int uc = X >> 1, vc = Y >> 1, wc = Z >> 1;
    float Xh = (float)X - 0.5f, Yh = (float)Y - 0.5f, Zh = (float)Z - 0.5f;
    float exf = (float)(X - 2*uc) - 0.5f;
    float eyf = (float)(Y - 2*vc) - 0.5f;
    float ezf = (float)(Z - 2*wc) - 0.5f;

    int pci = (uc+3)*PD2 + (vc+3)*PD + (wc+3);
    int pbase = pci*32;             // byte offset into param records (32 B each)
    int fbase = pci*32 + h*8;       // f16-element offset into feature records (32 elems each)

    int vc0 = Y0 >> 1, wc0 = Z0 >> 1;
    bool inter = (uc >= 3 && uc <= 28 && vc0 >= 3 && vc0 <= 25 && wc0 >= 3 && wc0 <= 25);

    f32x2 num2[4][4];
#pragma unroll
    for (int r = 0; r < 4; ++r)
#pragma unroll
        for (int p = 0; p < 4; ++p) num2[r][p] = {0.f, 0.f};
    float den = 0.f, M = TBIG;

    if (inter)
        body<true>(param4, featH, par, pbase, fbase, jcount, R2i, uc, vc, wc,
                   exf, eyf, ezf, Xh, Yh, Zh, G0, G1, G2, num2, den, M);
    else
        body<false>(param4, featH, par, pbase, fbase, jcount, R2i, uc, vc, wc,
                    exf, eyf, ezf, Xh, Yh, Zh, G0, G1, G2, num2, den, M);

    // ---- cross-parity merge via LDS (scale-reconciled per quad member, exact) ----
    float* mp = &mbuf[q][l][0];
    if (par) {
#pragma unroll
        for (int r = 0; r < 4; ++r)
#pragma unroll
            for (int p = 0; p < 4; ++p) {
                mp[r*8 + 2*p]     = num2[r][p].x;
                mp[r*8 + 2*p + 1] = num2[r][p].y;
            }
        mp[32] = den;
        mp[33] = M;
    }
    __syncthreads();
    if (par) return;

    float denoth = mp[32], Moth = mp[33];
    float Mc = fminf(M, Moth);
    float fs = fast_exp2((Mc - M) * LOG2E);
    float fo = fast_exp2((Mc - Moth) * LOG2E);
    den = den*fs + denoth*fo;
    // per-quad-member merge factors (num2[r] is at voxel-r's scale on BOTH parities)
    float fs1 = __shfl_xor(fs, 1), fo1 = __shfl_xor(fo, 1);
    float fs8 = __shfl_xor(fs, 8), fo8 = __shfl_xor(fo, 8);
    float fs9 = __shfl_xor(fs, 9), fo9 = __shfl_xor(fo, 9);
    f32x2 fsv[4] = {{fs,fs},{fs1,fs1},{fs8,fs8},{fs9,fs9}};
    f32x2 fov[4] = {{fo,fo},{fo1,fo1},{fo8,fo8},{fo9,fo9}};
#pragma unroll
    for (int r = 0; r < 4; ++r)
#pragma unroll
        for (int p = 0; p < 4; ++p) {
            f32x2 o = {mp[r*8 + 2*p], mp[r*8 + 2*p + 1]};
            num2[r][p] = num2[r][p]*fsv[r] + o*fov[r];
        }

    // ---- normalize + stores ----
    float invd = 1.0f / fmaxf(den, 1e-8f);
    float i1 = __shfl_xor(invd, 1), i8 = __shfl_xor(invd, 8), i9 = __shfl_xor(invd, 9);
    float* ob = out + (size_t)(h*8) * 262144;
#pragma unroll
    for (int p = 0; p < 4; ++p) {
        f32x2 v0 = num2[0][p], v1 = num2[1][p], v2 = num2[2][p], v3 = num2[3][p];
        ob[(2*p)*262144 + vox]          = v0.x * invd;
        ob[(2*p+1)*262144 + vox]        = v0.y * invd;
        ob[(2*p)*262144 + (vox ^ 1)]    = v1.x * i1;
        ob[(2*p+1)*262144 + (vox ^ 1)]  = v1.y * i1;
        ob[(2*p)*262144 + (vox ^ 64)]   = v2.x * i8;
        ob[(2*p+1)*262144 + (vox ^ 64)] = v2.y * i8;
        ob[(2*p)*262144 + (vox ^ 65)]   = v3.x * i9;
        ob[(2*p+1)*262144 + (vox ^ 65)] = v3.y * i9;
    }
}

// ---------------- launch ----------------
extern "C" void kernel_launch(void* const* d_in, const int* in_sizes, int n_in,
                              void* d_out, int out_size, void* d_ws, size_t ws_size,
                              hipStream_t stream) {
    const float* feat  = (const float*)d_in[0];   // [1][32][32][32][32]
    const float* guide = (const float*)d_in[1];   // [1][3][64][64][64]
    const float* sxr = (const float*)d_in[2];
    const float* syr = (const float*)d_in[3];
    const float* szr = (const float*)d_in[4];
    const float* srr = (const float*)d_in[5];
    float* out = (float*)d_out;                   // [1][32][64][64][64]

    char* ws = (char*)d_ws;
    float4* param4  = (float4*)ws;                     // 54872*32 B = 1.76 MB (padded, A/B interleaved)
    float* sigEff   = (float*)(ws + 2097152);          // 128 KB
    _Float16* featH = (_Float16*)(ws + 2228224);       // 54872*64 B = 3.51 MB (padded, f16 records)

    prepABpad<<<215, 256, 0, stream>>>(sxr, syr, szr, srr, guide, param4, sigEff);
    prepTpad<<<1024, 256, 0, stream>>>(feat, featH);
    prepBorder<<<215, 256, 0, stream>>>(featH);
    jbu_main<<<2048, 256, 0, stream>>>(guide, param4, sigEff, featH, out);
}

// Round 9
// 109.462 us; speedup vs baseline: 1.3366x; 1.3366x over previous
//
#include <hip/hip_runtime.h>

typedef float f32x2 __attribute__((ext_vector_type(2)));
typedef _Float16 h2 __attribute__((ext_vector_type(2)));

constexpr float LOG2E = 1.4426950408889634f;
#define TBIG 3.0e38f
#define PD 38          // padded grid dim (32 + 2*3 halo)
#define PD2 1444       // 38*38
#define NPC 54872      // 38^3 padded cells

// ---- per-parity offset table entries (123 offsets r2<=9 sorted by r2, split even/odd) ----
struct Ent { int e0; int r2; float fx, fy, fz; int dxi, dyi, dzi; };  // 32 B
struct Tabs { Ent e[2][62]; };
constexpr Tabs make_tabs() {
    int dxs[123], dys[123], dzs[123]; int n = 0;
    for (int rr = 0; rr <= 9; ++rr)
        for (int a = -3; a <= 3; ++a)
            for (int b = -3; b <= 3; ++b)
                for (int c = -3; c <= 3; ++c)
                    if (a*a + b*b + c*c == rr) { dxs[n]=a; dys[n]=b; dzs[n]=c; ++n; }
    Tabs T{};
    for (int p = 0; p < 2; ++p)
        for (int j = 0; j < 62; ++j) {
            int k = 2*j + p;
            if (k < 123) {
                int a = dxs[k], b = dys[k], c = dzs[k];
                int tci = (a*PD + b)*PD + c;
                T.e[p][j].e0 = tci*32;           // param byte offset; feat byte offset = e0*2
                T.e[p][j].r2 = a*a + b*b + c*c;
                T.e[p][j].fx = 2.f*a; T.e[p][j].fy = 2.f*b; T.e[p][j].fz = 2.f*c;
                T.e[p][j].dxi = a; T.e[p][j].dyi = b; T.e[p][j].dzi = c;
            } else {
                T.e[p][j].e0 = 0; T.e[p][j].r2 = 999;
            }
        }
    return T;
}
__constant__ Tabs TB = make_tabs();

__device__ __forceinline__ float fast_exp2(float x) { return __builtin_amdgcn_exp2f(x); }

// ---------------- prep AB (padded): sigma reciprocals + guide downsample + sigEff ----------------
__device__ __forceinline__ void mk_taps(int j, int idx[4], float wt[4]) {
    float s = 0.f;
#pragma unroll
    for (int k = 0; k < 4; ++k) {
        int i = 2*j - 1 + k;
        float w = (k == 0 || k == 3) ? 0.25f : 0.75f;
        bool ok = (i >= 0) && (i < 64);
        wt[k] = ok ? w : 0.f;
        idx[k] = ok ? i : 0;
        s += wt[k];
    }
    float inv = 1.f / s;
#pragma unroll
    for (int k = 0; k < 4; ++k) wt[k] *= inv;
}

__global__ void prepABpad(const float* __restrict__ sxr, const float* __restrict__ syr,
                          const float* __restrict__ szr, const float* __restrict__ srr,
                          const float* __restrict__ guide,
                          float4* __restrict__ param4, float* __restrict__ sigEff) {
    int t = blockIdx.x * 256 + threadIdx.x;
    if (t >= NPC) return;
    int pu = t / PD2; int rem = t - pu*PD2; int pv = rem / PD; int pw = rem - pv*PD;
    int u = min(max(pu-3, 0), 31), v = min(max(pv-3, 0), 31), w = min(max(pw-3, 0), 31);
    int ci = (u*32 + v)*32 + w;
    float sx = fmaxf(expf(sxr[ci]), 1e-6f);
    float sy = fmaxf(expf(syr[ci]), 1e-6f);
    float sz = fmaxf(expf(szr[ci]), 1e-6f);
    float sr = fmaxf(expf(srr[ci]), 1e-6f);
    param4[2*t] = make_float4(0.5f/(sx*sx), 0.5f/(sy*sy), 0.5f/(sz*sz), 1.0f/(2.0f*sr*sr + 1e-8f));
    if (pu-3 == u && pv-3 == v && pw-3 == w) sigEff[ci] = fmaxf(sx, fmaxf(sy, sz));

    int iu[4], iv[4], iw[4];
    float wu[4], wv[4], ww[4];
    mk_taps(u, iu, wu); mk_taps(v, iv, wv); mk_taps(w, iw, ww);
    float g0 = 0.f, g1 = 0.f, g2 = 0.f;
#pragma unroll
    for (int a = 0; a < 4; ++a)
#pragma unroll
        for (int b = 0; b < 4; ++b) {
            float wab = wu[a]*wv[b];
            int base = iu[a]*4096 + iv[b]*64;
#pragma unroll
            for (int c = 0; c < 4; ++c) {
                float wt = wab*ww[c];
                int gi = base + iw[c];
                g0 += wt*guide[gi];
                g1 += wt*guide[262144 + gi];
                g2 += wt*guide[524288 + gi];
            }
        }
    param4[2*t + 1] = make_float4(g0, g1, g2, 0.f);
}

// ---------------- prep T: feat [c][u][v][w] -> padded featH [pu][pv][pw][c] f16 (interior) ----------------
__global__ void prepTpad(const float* __restrict__ feat, _Float16* __restrict__ featH) {
    __shared__ float tile[32][33];
    int uv = blockIdx.x;
    int u = uv >> 5, v = uv & 31;
    int col = threadIdx.x & 31;
    int row = threadIdx.x >> 5;
#pragma unroll
    for (int it = 0; it < 4; ++it) {
        int c = row + it*8;
        tile[c][col] = feat[((c*32 + u)*32 + v)*32 + col];
    }
    __syncthreads();
#pragma unroll
    for (int it = 0; it < 4; ++it) {
        int w = row + it*8;
        int pci = (u+3)*PD2 + (v+3)*PD + (w+3);
        featH[pci*32 + col] = (_Float16)tile[col][w];
    }
}

// ---------------- prep border: replicate edge feature records into the halo ----------------
__global__ void prepBorder(_Float16* __restrict__ featH) {
    int t = blockIdx.x * 256 + threadIdx.x;
    if (t >= NPC) return;
    int pu = t / PD2; int rem = t - pu*PD2; int pv = rem / PD; int pw = rem - pv*PD;
    int u = min(max(pu-3, 0), 31), v = min(max(pv-3, 0), 31), w = min(max(pw-3, 0), 31);
    if (pu-3 == u && pv-3 == v && pw-3 == w) return;
    int src = ((u+3)*PD2 + (v+3)*PD + (w+3))*32;
    uint4* d = (uint4*)(featH + t*32);
    const uint4* s = (const uint4*)(featH + src);
    d[0] = s[0]; d[1] = s[1]; d[2] = s[2]; d[3] = s[3];
}

// ---- weight term (shared by both passes) ----
template<bool INTER>
__device__ __forceinline__ float weight_tt(const char* __restrict__ pb, int voffp,
                                           const Ent& E, int R2i,
                                           int uc, int vc, int wc,
                                           float exf, float eyf, float ezf,
                                           float Xh, float Yh, float Zh,
                                           float G0, float G1, float G2) {
    float4 A  = *(const float4*)(pb + (unsigned)voffp);
    float4 Bv = *(const float4*)(pb + (unsigned)voffp + 16);
    float ddx, ddy, ddz;
    if (INTER) {
        ddx = exf - E.fx;
        ddy = eyf - E.fy;
        ddz = ezf - E.fz;
    } else {
        int Ui = min(max(uc + E.dxi, 0), 31);
        int Vi = min(max(vc + E.dyi, 0), 31);
        int Wi = min(max(wc + E.dzi, 0), 31);
        ddx = fmaf(-2.f, (float)Ui, Xh);
        ddy = fmaf(-2.f, (float)Vi, Yh);
        ddz = fmaf(-2.f, (float)Wi, Zh);
    }
    float tt = fmaf(ddx*ddx, A.x, fmaf(ddy*ddy, A.y, ddz*ddz*A.z));
    float d0 = G0 - Bv.x, d1 = G1 - Bv.y, d2 = G2 - Bv.z;
    tt = fmaf(fmaf(d0, d0, fmaf(d1, d1, d2*d2)), A.w, tt);
    return (E.r2 <= R2i) ? tt : TBIG;
}

template<bool INTER>
__device__ __forceinline__ void run_body(const char* __restrict__ pb, const char* __restrict__ fb,
                                         int par, int jcount, int pbase, int fbase, int R2i,
                                         int uc, int vc, int wc,
                                         float exf, float eyf, float ezf,
                                         float Xh, float Yh, float Zh,
                                         float G0, float G1, float G2,
                                         float* sx_my, const float* sx_oth,
                                         f32x2 (&num2)[4][4], float& den, float& ML) {
    // ---- pass 1: exact per-voxel min of tt over my offsets ----
    float tmin = TBIG;
#pragma unroll 2
    for (int j = 0; j < jcount; ++j) {
        Ent E = TB.e[par][j];
        int voffp = pbase + E.e0;
        float tt = weight_tt<INTER>(pb, voffp, E, R2i, uc, vc, wc,
                                    exf, eyf, ezf, Xh, Yh, Zh, G0, G1, G2);
        tmin = fminf(tmin, tt);
    }
    *sx_my = tmin;
    __syncthreads();
    tmin = fminf(tmin, *sx_oth);
    ML = tmin * LOG2E;

    // ---- pass 2: branch-free accumulate at exact shared scale ----
#pragma unroll 2
    for (int j = 0; j < jcount; ++j) {
        Ent E = TB.e[par][j];
        int voffp = pbase + E.e0;
        int vofff = fbase + E.e0*2;
        float tt = weight_tt<INTER>(pb, voffp, E, R2i, uc, vc, wc,
                                    exf, eyf, ezf, Xh, Yh, Zh, G0, G1, G2);
        float wgt = fast_exp2(fmaf(tt, -LOG2E, ML));   // masked: -inf -> 0
        den += wgt;
        float w1 = __shfl_xor(wgt, 1), w8 = __shfl_xor(wgt, 8), w9 = __shfl_xor(wgt, 9);
        float4 F = *(const float4*)(fb + (unsigned)vofff);
        h2 q0 = __builtin_bit_cast(h2, F.x);
        h2 q1 = __builtin_bit_cast(h2, F.y);
        h2 q2 = __builtin_bit_cast(h2, F.z);
        h2 q3 = __builtin_bit_cast(h2, F.w);
        f32x2 f0 = {(float)q0.x, (float)q0.y};
        f32x2 f1 = {(float)q1.x, (float)q1.y};
        f32x2 f2 = {(float)q2.x, (float)q2.y};
        f32x2 f3 = {(float)q3.x, (float)q3.y};
        f32x2 w0v = {wgt, wgt}, w1v = {w1, w1}, w2v = {w8, w8}, w3v = {w9, w9};
        num2[0][0] += f0*w0v; num2[0][1] += f1*w0v; num2[0][2] += f2*w0v; num2[0][3] += f3*w0v;
        num2[1][0] += f0*w1v; num2[1][1] += f1*w1v; num2[1][2] += f2*w1v; num2[1][3] += f3*w1v;
        num2[2][0] += f0*w2v; num2[2][1] += f1*w2v; num2[2][2] += f2*w2v; num2[2][3] += f3*w2v;
        num2[3][0] += f0*w3v; num2[3][1] += f1*w3v; num2[3][2] += f2*w3v; num2[3][3] += f3*w3v;
    }
}

// ---- main: 2 waves per 8x8 (Y,Z) tile (even/odd offsets), quads share LR cell ----
__global__ __launch_bounds__(256, 4)
void jbu_main(const float* __restrict__ guide, const float4* __restrict__ param4,
              const float* __restrict__ sigEff, const _Float16* __restrict__ featH,
              float* __restrict__ out) {
    __shared__ float mbuf[2][64][33];   // parity-1 waves park {num[32], den}
    __shared__ float sxch[2][2][64];    // per-tile per-parity tmin exchange
    int tid = threadIdx.x;
    int widx = tid >> 6;
    int l = tid & 63;
    int par = __builtin_amdgcn_readfirstlane(widx & 1);
    int q = __builtin_amdgcn_readfirstlane(widx >> 1);
    // XCD-bijective swizzle: 2048 blocks, XCD k owns X in [8k, 8k+8)
    int bsw = (blockIdx.x & 7) * 256 + (blockIdx.x >> 3);
    int tIdx = bsw * 2 + q;             // 4096 tiles
    int X = __builtin_amdgcn_readfirstlane(tIdx >> 6);
    int Y0 = ((tIdx >> 3) & 7) << 3;
    int Z0 = (tIdx & 7) << 3;
    int y = l >> 3, z = l & 7;
    int Y = Y0 + y, Z = Z0 + z;
    int h = ((y & 1) << 1) | (z & 1);
    int vox = (X << 12) + (Y << 6) + Z;

    float G0 = guide[vox];
    float G1 = guide[262144 + vox];
    float G2 = guide[524288 + vox];

    // sigma_eff_hr: 2x trilinear upsample with clamped taps -> R2i
    int x0 = max((X-1) >> 1, 0), x1 = min(((X-1) >> 1) + 1, 31);
    int y0 = max((Y-1) >> 1, 0), y1 = min(((Y-1) >> 1) + 1, 31);
    int z0 = max((Z-1) >> 1, 0), z1 = min(((Z-1) >> 1) + 1, 31);
    float wx1 = (X & 1) ? 0.25f : 0.75f, wx0 = 1.f - wx1;
    float wy1 = (Y & 1) ? 0.25f : 0.75f, wy0 = 1.f - wy1;
    float wz1 = (Z & 1) ? 0.25f : 0.75f, wz0 = 1.f - wz1;
#define SG(i, j, k) sigEff[((i)*32 + (j))*32 + (k)]
    float se =
        wx0*(wy0*(wz0*SG(x0,y0,z0) + wz1*SG(x0,y0,z1)) +
             wy1*(wz0*SG(x0,y1,z0) + wz1*SG(x0,y1,z1))) +
        wx1*(wy0*(wz0*SG(x1,y0,z0) + wz1*SG(x1,y0,z1)) +
             wy1*(wz0*SG(x1,y1,z0) + wz1*SG(x1,y1,z1)));
#undef SG
    float Rf = fminf(fmaxf(ceilf(2.f*se), 1.f), 3.f);
    int R2i = (int)(Rf*Rf + 0.5f);
    bool a9 = __any((int)(R2i >= 9));
    bool a4 = __any((int)(R2i >= 4));
    int nmax = a9 ? 123 : (a4 ? 33 : 7);
    int jcount = __builtin_amdgcn_readfirstlane((nmax - par + 1) >> 1);

    int uc = X >> 1, vc = Y >> 1, wc = Z >> 1;
    float Xh = (float)X - 0.5f, Yh = (float)Y - 0.5f, Zh = (float)Z - 0.5f;
    float exf = (float)(X - 2*uc) - 0.5f;
    float eyf = (float)(Y - 2*vc) - 0.5f;
    float ezf = (float)(Z - 2*wc) - 0.5f;

    int pci = (uc+3)*PD2 + (vc+3)*PD + (wc+3);
    int pbase = pci*32;             // param record byte offset (32 B records)
    int fbase = pci*64 + h*16;      // feat record byte offset (64 B records, my 16-B quarter)

    int vc0 = Y0 >> 1, wc0 = Z0 >> 1;
    bool inter = (uc >= 3 && uc <= 28 && vc0 >= 3 && vc0 <= 25 && wc0 >= 3 && wc0 <= 25);

    f32x2 num2[4][4];
#pragma unroll
    for (int r = 0; r < 4; ++r)
#pragma unroll
        for (int p = 0; p < 4; ++p) num2[r][p] = {0.f, 0.f};
    float den = 0.f, ML = 0.f;

    const char* pb = (const char*)param4;
    const char* fb = (const char*)featH;
    float* sx_my  = &sxch[q][par][l];
    const float* sx_oth = &sxch[q][par ^ 1][l];

    if (inter)
        run_body<true>(pb, fb, par, jcount, pbase, fbase, R2i, uc, vc, wc,
                       exf, eyf, ezf, Xh, Yh, Zh, G0, G1, G2, sx_my, sx_oth, num2, den, ML);
    else
        run_body<false>(pb, fb, par, jcount, pbase, fbase, R2i, uc, vc, wc,
                        exf, eyf, ezf, Xh, Yh, Zh, G0, G1, G2, sx_my, sx_oth, num2, den, ML);

    // ---- cross-parity merge via LDS (same scale ML on both parities -> plain add) ----
    float* mp = &mbuf[q][l][0];
    if (par) {
#pragma unroll
        for (int r = 0; r < 4; ++r)
#pragma unroll
            for (int p = 0; p < 4; ++p) {
                mp[r*8 + 2*p]     = num2[r][p].x;
                mp[r*8 + 2*p + 1] = num2[r][p].y;
            }
        mp[32] = den;
    }
    __syncthreads();
    if (par) return;

#pragma unroll
    for (int r = 0; r < 4; ++r)
#pragma unroll
        for (int p = 0; p < 4; ++p) {
            num2[r][p].x += mp[r*8 + 2*p];
            num2[r][p].y += mp[r*8 + 2*p + 1];
        }
    den += mp[32];

    // ---- normalize + stores ----
    float invd = 1.0f / fmaxf(den, 1e-8f);
    float i1 = __shfl_xor(invd, 1), i8 = __shfl_xor(invd, 8), i9 = __shfl_xor(invd, 9);
    float* ob = out + (size_t)(h*8) * 262144;
#pragma unroll
    for (int p = 0; p < 4; ++p) {
        f32x2 v0 = num2[0][p], v1 = num2[1][p], v2 = num2[2][p], v3 = num2[3][p];
        ob[(2*p)*262144 + vox]          = v0.x * invd;
        ob[(2*p+1)*262144 + vox]        = v0.y * invd;
        ob[(2*p)*262144 + (vox ^ 1)]    = v1.x * i1;
        ob[(2*p+1)*262144 + (vox ^ 1)]  = v1.y * i1;
        ob[(2*p)*262144 + (vox ^ 64)]   = v2.x * i8;
        ob[(2*p+1)*262144 + (vox ^ 64)] = v2.y * i8;
        ob[(2*p)*262144 + (vox ^ 65)]   = v3.x * i9;
        ob[(2*p+1)*262144 + (vox ^ 65)] = v3.y * i9;
    }
}

// ---------------- launch ----------------
extern "C" void kernel_launch(void* const* d_in, const int* in_sizes, int n_in,
                              void* d_out, int out_size, void* d_ws, size_t ws_size,
                              hipStream_t stream) {
    const float* feat  = (const float*)d_in[0];   // [1][32][32][32][32]
    const float* guide = (const float*)d_in[1];   // [1][3][64][64][64]
    const float* sxr = (const float*)d_in[2];
    const float* syr = (const float*)d_in[3];
    const float* szr = (const float*)d_in[4];
    const float* srr = (const float*)d_in[5];
    float* out = (float*)d_out;                   // [1][32][64][64][64]

    char* ws = (char*)d_ws;
    float4* param4  = (float4*)ws;                     // 54872*32 B = 1.76 MB (padded, A/B interleaved)
    float* sigEff   = (float*)(ws + 2097152);          // 128 KB
    _Float16* featH = (_Float16*)(ws + 2228224);       // 54872*64 B = 3.51 MB (padded, f16 records)

    prepABpad<<<215, 256, 0, stream>>>(sxr, syr, szr, srr, guide, param4, sigEff);
    prepTpad<<<1024, 256, 0, stream>>>(feat, featH);
    prepBorder<<<215, 256, 0, stream>>>(featH);
    jbu_main<<<2048, 256, 0, stream>>>(guide, param4, sigEff, featH, out);
}